// Round 8
// baseline (293.261 us; speedup 1.0000x reference)
//
#include <hip/hip_runtime.h>
#include <math.h>

// Problem constants (from reference)
#define BB 8
#define SS 4096
#define DD 512
#define HH 512
#define MM (BB*SS)          // 32768 rows

// Scan chunking
constexpr int TCH = 64;              // timesteps per chunk
constexpr int NC  = SS / TCH;        // 64 chunks
constexpr int BH  = BB * HH;         // 4096 channels

// MFMA GEMM tiling
constexpr int BM = 128;              // rows per block (= 2 chunks of 64 s)
constexpr int BN = 64;               // cols per block (per weight matrix)
constexpr int BK = 64;               // k per stage

typedef short  short8  __attribute__((ext_vector_type(8)));
typedef float  float4v __attribute__((ext_vector_type(4)));

__device__ inline unsigned short f2bf(float f) {
    union { float f; unsigned u; } v; v.f = f;
    unsigned r = v.u + 0x7FFF + ((v.u >> 16) & 1);   // RNE
    return (unsigned short)(r >> 16);
}
__device__ inline float bf_lo(unsigned u) {          // low 16 bits -> float
    union { unsigned u; float f; } x; x.u = u << 16; return x.f;
}
__device__ inline float bf_hi(unsigned u) {          // high 16 bits -> float
    union { unsigned u; float f; } x; x.u = u & 0xffff0000u; return x.f;
}
__device__ inline float fast_rcp(float x) {          // v_rcp_f32, ~1ulp(22b)
    return __builtin_amdgcn_rcpf(x);
}

__device__ inline void async_copy16(const void* g, void* l) {
    __builtin_amdgcn_global_load_lds(
        (const __attribute__((address_space(1))) void*)g,
        (__attribute__((address_space(3))) void*)l, 16, 0, 0);
}

// ---------------------------------------------------------------------------
// fp32 -> bf16 conversion for X (8192 blocks) and the 4 weights (4x128 blocks)
// in a single launch.
// ---------------------------------------------------------------------------
__global__ __launch_bounds__(256)
void conv_all(const float* __restrict__ x,
              const float* __restrict__ w0, const float* __restrict__ w1,
              const float* __restrict__ w2, const float* __restrict__ w3,
              short* __restrict__ Xbf, short* __restrict__ Wbf)
{
    constexpr int XBLK = MM * DD / 8 / 256;   // 8192
    constexpr int WBLK = HH * DD / 8 / 256;   // 128
    const int bid = blockIdx.x;
    const float* src; short* dst; size_t base;
    if (bid < XBLK) {
        src = x; dst = Xbf;
        base = ((size_t)bid * 256 + threadIdx.x) * 8;
    } else {
        const int idx  = bid - XBLK;
        const int wsel = idx / WBLK;
        src = (wsel == 0) ? w0 : (wsel == 1) ? w1 : (wsel == 2) ? w2 : w3;
        dst = Wbf + (size_t)wsel * HH * DD;
        base = ((size_t)(idx % WBLK) * 256 + threadIdx.x) * 8;
    }
    float4 a = *(const float4*)(src + base);
    float4 b = *(const float4*)(src + base + 4);
    short8 r;
    r[0] = f2bf(a.x); r[1] = f2bf(a.y); r[2] = f2bf(a.z); r[3] = f2bf(a.w);
    r[4] = f2bf(b.x); r[5] = f2bf(b.y); r[6] = f2bf(b.z); r[7] = f2bf(b.w);
    *(short8*)(dst + base) = r;
}

// ---------------------------------------------------------------------------
// MFMA gate GEMM + fused chunk-summary scan.
//   kz = X[m,:]·Wz[n,:]+bz[n], kh = X[m,:]·Wh[n,:]+bh[n]
//   a = sigmoid(-kz); v = (1-a)*g(kh); AV stores pack_bf16(v, a)
//
// K-loop: round-4 proven version, byte-identical (T2 XOR-swizzle +
// 2-phase FULL-DRAIN). CONDEMNED (measured): counted-vmcnt (r1,r3 races);
// in-phase global B loads (r5 FIFO serialization); cross-barrier B register
// double-buffer (r6 VGPR spill).
//
// This revision changes ONLY the epilogue + AV layout:
//  * AV is CHUNK-MAJOR: AV[((cg*HH + n)*TCH + t], cg = global chunk m/64.
//    Each thread's C-fragment (4 consecutive t at fixed n) becomes ONE
//    direct global_store_dwordx4; a quad-group (lanes l,l+16,l+32,l+48)
//    fills an exact 64B line -> perfect write coalescing WITHOUT the LDS
//    round-trip. The old lds_av tile, its __syncthreads, the 32-dword
//    store loop, and the LDS-read chunk summary are all deleted.
//  * Chunk summaries computed in-register from the packed (rounded) a/v:
//    per-thread 4-step segment, then 2-step __shfl_xor tree over the quad
//    dimension (t-ordered composition (Al,Vl)o(Ar,Vr)=(AlAr, Ar*Vl+Vr)),
//    then in-thread composition over mi. Same values as before up to fp
//    regrouping of the 64-term product.
// ---------------------------------------------------------------------------
__global__ __launch_bounds__(256)
void gemm_gate_mfma(const short* __restrict__ Xg, const short* __restrict__ Wz,
                    const float* __restrict__ bz, const short* __restrict__ Wh,
                    const float* __restrict__ bh, unsigned* __restrict__ AV,
                    float2* __restrict__ cAV)
{
    __shared__ char smem[65536];               // 2 x 32KB staging
    short* lds = (short*)smem;
    constexpr int BUFS = 16384;                // shorts per buffer (32 KB)
    constexpr int ZOFF = BM * BK;              // 8192  (within buffer)
    constexpr int HOFF = ZOFF + BN * BK;       // 12288 (within buffer)
    constexpr int NIT  = DD / BK;              // 8 K-steps

    const int t    = threadIdx.x;
    const int wave = t >> 6;
    const int lane = t & 63;
    const int col16 = lane & 15;
    const int quad  = lane >> 4;
    const int wm = wave >> 1;          // 0/1: which 64-row half (= chunk)
    const int wn = wave & 1;           // 0/1: which 32-col half
    const int m0 = blockIdx.x * BM;
    const int n0 = blockIdx.y * BN;

    float4v accz[4][2], acch[4][2];
    #pragma unroll
    for (int i = 0; i < 4; ++i)
        #pragma unroll
        for (int j = 0; j < 2; ++j) {
            accz[i][j] = (float4v){0.f, 0.f, 0.f, 0.f};
            acch[i][j] = (float4v){0.f, 0.f, 0.f, 0.f};
        }

    const int lr  = lane >> 3;                 // 0..7 row within an 8-row wave-load
    const int lcs = (((lane & 7) ^ lr) * 8);   // PRE-SWIZZLED global col (bf16 units)

    // one stage = 8 async copies / wave (X:4, Wz:2, Wh:2)
    auto stage = [&](int buf, int k0) {
        short* L = lds + buf * BUFS;
        #pragma unroll
        for (int i = 0; i < 4; ++i) {
            const int r0 = wave * 32 + i * 8;
            async_copy16(Xg + (size_t)(m0 + r0 + lr) * DD + k0 + lcs,
                         &L[r0 * BK]);
        }
        #pragma unroll
        for (int i = 0; i < 2; ++i) {
            const int r0 = wave * 16 + i * 8;
            async_copy16(Wz + (size_t)(n0 + r0 + lr) * DD + k0 + lcs,
                         &L[ZOFF + r0 * BK]);
            async_copy16(Wh + (size_t)(n0 + r0 + lr) * DD + k0 + lcs,
                         &L[HOFF + r0 * BK]);
        }
    };

    // prologue: fill buf0, full drain, barrier
    stage(0, 0);
    asm volatile("s_waitcnt vmcnt(0)" ::: "memory");
    __builtin_amdgcn_s_barrier();
    asm volatile("" ::: "memory");

    const int swz = (col16 & 7) * 8;           // read-side XOR (bf16 units)

    #pragma unroll
    for (int it = 0; it < NIT; ++it) {
        // issue next-tile staging first: HBM latency hides under this tile's MFMAs
        if (it + 1 < NIT) stage((it + 1) & 1, (it + 1) * BK);

        const short* L = lds + (it & 1) * BUFS;
        #pragma unroll
        for (int kk = 0; kk < 2; ++kk) {
            const int ko = (kk * 32 + quad * 8) ^ swz;   // swizzled col offset
            short8 af[4], bzf[2], bhf[2];
            #pragma unroll
            for (int mi = 0; mi < 4; ++mi)
                af[mi] = *(const short8*)&L[(wm*64 + mi*16 + col16) * BK + ko];
            #pragma unroll
            for (int nj = 0; nj < 2; ++nj) {
                bzf[nj] = *(const short8*)&L[ZOFF + (wn*32 + nj*16 + col16) * BK + ko];
                bhf[nj] = *(const short8*)&L[HOFF + (wn*32 + nj*16 + col16) * BK + ko];
            }
            #pragma unroll
            for (int mi = 0; mi < 4; ++mi)
                #pragma unroll
                for (int nj = 0; nj < 2; ++nj) {
                    accz[mi][nj] = __builtin_amdgcn_mfma_f32_16x16x32_bf16(af[mi], bzf[nj], accz[mi][nj], 0, 0, 0);
                    acch[mi][nj] = __builtin_amdgcn_mfma_f32_16x16x32_bf16(af[mi], bhf[nj], acch[mi][nj], 0, 0, 0);
                }
        }
        // drain: next-tile stages landed, this tile's ds_reads retired.
        asm volatile("s_waitcnt vmcnt(0) lgkmcnt(0)" ::: "memory");
        __builtin_amdgcn_s_barrier();
        asm volatile("" ::: "memory");
    }

    // ---- epilogue: gates -> packed bf16, direct chunk-major stores ----
    // C/D layout: col=lane&15 (-> n), row=quad*4+reg (-> m) (m89/m91-verified)
    // m_local = wm*64 + mi*16 + quad*4 + reg  ->  t = mi*16+quad*4+reg,
    // chunk = wm.  AV addr = (cg*HH + n)*TCH + t, uint4 = 4 consecutive t.
    {
        const int b  = m0 >> 12;                    // batch
        const int cw = ((m0 & 4095) >> 6) + wm;     // chunk within sequence
        const size_t cg = (size_t)(m0 >> 6) + wm;   // global chunk (b*64 + cw)

        #pragma unroll
        for (int nj = 0; nj < 2; ++nj) {
            const int ln = wn*32 + nj*16 + col16;
            const int n  = n0 + ln;
            const float bzn = bz[n], bhn = bh[n];
            float cA = 1.0f, cV = 0.0f;             // running chunk composite
            #pragma unroll
            for (int mi = 0; mi < 4; ++mi) {
                unsigned pk[4];
                float sA = 1.0f, sV = 0.0f;         // this thread's 4-t segment
                #pragma unroll
                for (int reg = 0; reg < 4; ++reg) {
                    const float kz = accz[mi][nj][reg] + bzn;
                    const float kh = acch[mi][nj][reg] + bhn;
                    const float a  = fast_rcp(1.0f + __expf(kz));   // sigmoid(-kz)
                    const float sn = fast_rcp(1.0f + __expf(-kh));  // sigmoid(kh)
                    const float ht = (kh >= 0.0f) ? (kh + 0.5f) : sn;
                    const float v  = (1.0f - a) * ht;               // z * h_tilde
                    const unsigned u = ((unsigned)f2bf(v) << 16) | f2bf(a);
                    pk[reg] = u;
                    const float ar = bf_lo(u), vr = bf_hi(u);       // rounded
                    sV = fmaf(ar, sV, vr);          // t ascending within segment
                    sA *= ar;
                }
                *(uint4*)&AV[(cg * HH + n) * TCH + mi*16 + quad*4] =
                    make_uint4(pk[0], pk[1], pk[2], pk[3]);
                // quad-tree combine (t-order: quad ascending), 16-t composite
                {
                    float oA = __shfl_xor(sA, 16), oV = __shfl_xor(sV, 16);
                    float lA = (quad & 1) ? oA : sA, lV = (quad & 1) ? oV : sV;
                    float rA = (quad & 1) ? sA : oA, rV = (quad & 1) ? sV : oV;
                    sA = lA * rA; sV = fmaf(rA, lV, rV);
                    oA = __shfl_xor(sA, 32); oV = __shfl_xor(sV, 32);
                    lA = (quad & 2) ? oA : sA; lV = (quad & 2) ? oV : sV;
                    rA = (quad & 2) ? sA : oA; rV = (quad & 2) ? sV : oV;
                    sA = lA * rA; sV = fmaf(rA, lV, rV);
                }
                cV = fmaf(sA, cV, sV);              // compose mi segments in order
                cA = cA * sA;
            }
            if (quad == 0)
                cAV[(size_t)cw * BH + b * HH + n] = make_float2(cA, cV);
        }
    }
}

// ---------------------------------------------------------------------------
// Chunk-carry prefix: one thread per channel (b,h). Sequentially composes
// the 64 chunk summaries ONCE, emitting the entering-h for every chunk.
// Grid: 16 blocks x 256 threads = 4096 channels.
// ---------------------------------------------------------------------------
__global__ __launch_bounds__(256)
void chunk_prefix(const float2* __restrict__ cAV, float* __restrict__ H0)
{
    const int ch = blockIdx.x * 256 + threadIdx.x;   // b*HH + h
    float h = 0.5f;                                  // h0 = g(0) = 0.5
    #pragma unroll
    for (int c = 0; c < NC; ++c) {
        H0[(size_t)c * BH + ch] = h;
        const float2 s = cAV[(size_t)c * BH + ch];
        h = fmaf(s.x, h, s.y);
    }
}

// ---------------------------------------------------------------------------
// Scan apply (fp32 out, final layer). 1 channel/thread. Chunk-major AV:
// this thread's 64 timesteps are 256B CONTIGUOUS -> 16 uint4 loads
// (was 64 scalar strided). Carry from precomputed H0. NT store for `out`.
// ---------------------------------------------------------------------------
__global__ __launch_bounds__(256)
void scan_apply_f32(const unsigned* __restrict__ AV,
                    const float* __restrict__ H0,
                    float* __restrict__ out, float* __restrict__ finals)
{
    const int h = blockIdx.x * 256 + threadIdx.x;
    const int b = blockIdx.y;
    const int c = blockIdx.z;
    const int ch = b * HH + h;
    float hcur = H0[(size_t)c * BH + ch];
    const uint4* src = (const uint4*)(AV + ((size_t)(b * NC + c) * HH + h) * TCH);
    size_t base = ((size_t)(b * SS + c * TCH)) * HH + h;
    #pragma unroll
    for (int j = 0; j < TCH / 4; ++j) {
        const uint4 u = src[j];
        hcur = fmaf(bf_lo(u.x), hcur, bf_hi(u.x));
        __builtin_nontemporal_store(hcur, &out[base]);
        hcur = fmaf(bf_lo(u.y), hcur, bf_hi(u.y));
        __builtin_nontemporal_store(hcur, &out[base + HH]);
        hcur = fmaf(bf_lo(u.z), hcur, bf_hi(u.z));
        __builtin_nontemporal_store(hcur, &out[base + 2 * HH]);
        hcur = fmaf(bf_lo(u.w), hcur, bf_hi(u.w));
        __builtin_nontemporal_store(hcur, &out[base + 3 * HH]);
        base += 4 * HH;
    }
    if (c == NC - 1) finals[ch] = hcur;
}

// ---------------------------------------------------------------------------
// Scan apply (bf16 out): layer-0 hidden seq feeds layer-1's GEMM (Xbf is
// re-read soon -> normal stores). Same vectorized AV reads.
// ---------------------------------------------------------------------------
__global__ __launch_bounds__(256)
void scan_apply_bf16(const unsigned* __restrict__ AV,
                     const float* __restrict__ H0,
                     short* __restrict__ out, float* __restrict__ finals)
{
    const int h = blockIdx.x * 256 + threadIdx.x;
    const int b = blockIdx.y;
    const int c = blockIdx.z;
    const int ch = b * HH + h;
    float hcur = H0[(size_t)c * BH + ch];
    const uint4* src = (const uint4*)(AV + ((size_t)(b * NC + c) * HH + h) * TCH);
    size_t base = ((size_t)(b * SS + c * TCH)) * HH + h;
    #pragma unroll
    for (int j = 0; j < TCH / 4; ++j) {
        const uint4 u = src[j];
        hcur = fmaf(bf_lo(u.x), hcur, bf_hi(u.x));
        out[base] = (short)f2bf(hcur);
        hcur = fmaf(bf_lo(u.y), hcur, bf_hi(u.y));
        out[base + HH] = (short)f2bf(hcur);
        hcur = fmaf(bf_lo(u.z), hcur, bf_hi(u.z));
        out[base + 2 * HH] = (short)f2bf(hcur);
        hcur = fmaf(bf_lo(u.w), hcur, bf_hi(u.w));
        out[base + 3 * HH] = (short)f2bf(hcur);
        base += 4 * HH;
    }
    if (c == NC - 1) finals[ch] = hcur;
}

// ---------------------------------------------------------------------------
// Orchestration.  ws: AV(64MB) Xbf(32MB) Wbf(2MB) cAV(2MB) H0(1MB) ~ 101MB
// ---------------------------------------------------------------------------
extern "C" void kernel_launch(void* const* d_in, const int* in_sizes, int n_in,
                              void* d_out, int out_size, void* d_ws, size_t ws_size,
                              hipStream_t stream)
{
    const float* x   = (const float*)d_in[0];
    const float* wz0 = (const float*)d_in[1];
    const float* bz0 = (const float*)d_in[2];
    const float* wh0 = (const float*)d_in[3];
    const float* bh0 = (const float*)d_in[4];
    const float* wz1 = (const float*)d_in[5];
    const float* bz1 = (const float*)d_in[6];
    const float* wh1 = (const float*)d_in[7];
    const float* bh1 = (const float*)d_in[8];

    float* out    = (float*)d_out;                // (B,S,H) layer-2 hidden seq
    float* finals = out + (size_t)MM * HH;        // (L,B,1,H)

    unsigned* AV  = (unsigned*)d_ws;                      // chunk-major packed bf16 (v|a)
    short* Xbf    = (short*)(AV + (size_t)MM * HH);       // M*D bf16
    short* Wbf    = Xbf + (size_t)MM * DD;                // 4 * H*D bf16
    float2* cAV   = (float2*)(Wbf + (size_t)4 * HH * DD); // NC*BH float2
    float* H0     = (float*)(cAV + (size_t)NC * BH);      // NC*BH float

    short* Wz0 = Wbf;
    short* Wh0 = Wbf + (size_t)1 * HH * DD;
    short* Wz1 = Wbf + (size_t)2 * HH * DD;
    short* Wh1 = Wbf + (size_t)3 * HH * DD;

    const dim3 gg(MM / BM, HH / BN);       // 256 x 8
    const dim3 gs(HH / 256, BB, NC);       // 2 x 8 x 64 (1 channel/thread)

    // ---- conversions (one launch: X + all 4 weights) ----
    conv_all<<<MM * DD / 8 / 256 + 4 * (HH * DD / 8 / 256), 256, 0, stream>>>(
        x, wz0, wh0, wz1, wh1, Xbf, Wbf);

    // ---- layer 0 ----
    gemm_gate_mfma <<<gg, 256, 0, stream>>>(Xbf, Wz0, bz0, Wh0, bh0, AV, cAV);
    chunk_prefix   <<<BH / 256, 256, 0, stream>>>(cAV, H0);
    scan_apply_bf16<<<gs, 256, 0, stream>>>(AV, H0, Xbf, finals);             // finals[0]

    // ---- layer 1 ----
    gemm_gate_mfma <<<gg, 256, 0, stream>>>(Xbf, Wz1, bz1, Wh1, bh1, AV, cAV);
    chunk_prefix   <<<BH / 256, 256, 0, stream>>>(cAV, H0);
    scan_apply_f32 <<<gs, 256, 0, stream>>>(AV, H0, out, finals + BH);        // finals[1]
}

// Round 9
// 287.536 us; speedup vs baseline: 1.0199x; 1.0199x over previous
//
#include <hip/hip_runtime.h>
#include <math.h>

// Problem constants (from reference)
#define BB 8
#define SS 4096
#define DD 512
#define HH 512
#define MM (BB*SS)          // 32768 rows

// Scan chunking
constexpr int TCH = 64;              // timesteps per chunk
constexpr int NC  = SS / TCH;        // 64 chunks
constexpr int BH  = BB * HH;         // 4096 channels

// MFMA GEMM tiling
constexpr int BM = 128;              // rows per block (= 2 chunks of 64 s)
constexpr int BN = 64;               // cols per block (per weight matrix)
constexpr int BK = 64;               // k per stage

typedef short  short8  __attribute__((ext_vector_type(8)));
typedef float  float4v __attribute__((ext_vector_type(4)));

__device__ inline unsigned short f2bf(float f) {
    union { float f; unsigned u; } v; v.f = f;
    unsigned r = v.u + 0x7FFF + ((v.u >> 16) & 1);   // RNE
    return (unsigned short)(r >> 16);
}
__device__ inline float bf_lo(unsigned u) {          // low 16 bits -> float
    union { unsigned u; float f; } x; x.u = u << 16; return x.f;
}
__device__ inline float bf_hi(unsigned u) {          // high 16 bits -> float
    union { unsigned u; float f; } x; x.u = u & 0xffff0000u; return x.f;
}
__device__ inline float fast_rcp(float x) {          // v_rcp_f32, ~1ulp(22b)
    return __builtin_amdgcn_rcpf(x);
}

__device__ inline void async_copy16(const void* g, void* l) {
    __builtin_amdgcn_global_load_lds(
        (const __attribute__((address_space(1))) void*)g,
        (__attribute__((address_space(3))) void*)l, 16, 0, 0);
}

// ---------------------------------------------------------------------------
// fp32 -> bf16 conversion for X (8192 blocks) and the 4 weights (4x128 blocks)
// in a single launch.
// ---------------------------------------------------------------------------
__global__ __launch_bounds__(256)
void conv_all(const float* __restrict__ x,
              const float* __restrict__ w0, const float* __restrict__ w1,
              const float* __restrict__ w2, const float* __restrict__ w3,
              short* __restrict__ Xbf, short* __restrict__ Wbf)
{
    constexpr int XBLK = MM * DD / 8 / 256;   // 8192
    constexpr int WBLK = HH * DD / 8 / 256;   // 128
    const int bid = blockIdx.x;
    const float* src; short* dst; size_t base;
    if (bid < XBLK) {
        src = x; dst = Xbf;
        base = ((size_t)bid * 256 + threadIdx.x) * 8;
    } else {
        const int idx  = bid - XBLK;
        const int wsel = idx / WBLK;
        src = (wsel == 0) ? w0 : (wsel == 1) ? w1 : (wsel == 2) ? w2 : w3;
        dst = Wbf + (size_t)wsel * HH * DD;
        base = ((size_t)(idx % WBLK) * 256 + threadIdx.x) * 8;
    }
    float4 a = *(const float4*)(src + base);
    float4 b = *(const float4*)(src + base + 4);
    short8 r;
    r[0] = f2bf(a.x); r[1] = f2bf(a.y); r[2] = f2bf(a.z); r[3] = f2bf(a.w);
    r[4] = f2bf(b.x); r[5] = f2bf(b.y); r[6] = f2bf(b.z); r[7] = f2bf(b.w);
    *(short8*)(dst + base) = r;
}

// ---------------------------------------------------------------------------
// MFMA gate GEMM + fused chunk-summary scan.
//   kz = X[m,:]·Wz[n,:]+bz[n], kh = X[m,:]·Wh[n,:]+bh[n]
//   a = sigmoid(-kz); v = (1-a)*g(kh); AV[m*HH+n] = pack_bf16(v, a)
//
// K-loop: round-4 proven version, byte-identical (T2 XOR-swizzle +
// 2-phase FULL-DRAIN). CONDEMNED (measured): counted-vmcnt (r1,r3 races);
// in-phase global B loads (r5 FIFO serialization); cross-barrier B register
// double-buffer (r6 VGPR spill); chunk-major AV (r8: scan reads 4x the
// line-transactions, ~+40us on scans).
//
// Epilogue (r8-proven, retargeted to TIME-major AV):
//  * Direct dword stores: per (mi,reg) instruction, lanes 0-15 write 64B
//    contiguous (consecutive n) x 4 quads = 4 full lines -> coalesced
//    WITHOUT the LDS round-trip (r8 measured: conflicts 1.05e6 -> 0).
//  * Chunk summaries in-register from packed (rounded) a/v: per-thread
//    4-t segment, 2-step __shfl_xor tree over quads (t-ordered composition
//    (Al,Vl)o(Ar,Vr)=(AlAr, Ar*Vl+Vr)), then in-thread over mi (r8-verified).
// ---------------------------------------------------------------------------
__global__ __launch_bounds__(256)
void gemm_gate_mfma(const short* __restrict__ Xg, const short* __restrict__ Wz,
                    const float* __restrict__ bz, const short* __restrict__ Wh,
                    const float* __restrict__ bh, unsigned* __restrict__ AV,
                    float2* __restrict__ cAV)
{
    __shared__ char smem[65536];               // 2 x 32KB staging
    short* lds = (short*)smem;
    constexpr int BUFS = 16384;                // shorts per buffer (32 KB)
    constexpr int ZOFF = BM * BK;              // 8192  (within buffer)
    constexpr int HOFF = ZOFF + BN * BK;       // 12288 (within buffer)
    constexpr int NIT  = DD / BK;              // 8 K-steps

    const int t    = threadIdx.x;
    const int wave = t >> 6;
    const int lane = t & 63;
    const int col16 = lane & 15;
    const int quad  = lane >> 4;
    const int wm = wave >> 1;          // 0/1: which 64-row half (= chunk)
    const int wn = wave & 1;           // 0/1: which 32-col half
    const int m0 = blockIdx.x * BM;
    const int n0 = blockIdx.y * BN;

    float4v accz[4][2], acch[4][2];
    #pragma unroll
    for (int i = 0; i < 4; ++i)
        #pragma unroll
        for (int j = 0; j < 2; ++j) {
            accz[i][j] = (float4v){0.f, 0.f, 0.f, 0.f};
            acch[i][j] = (float4v){0.f, 0.f, 0.f, 0.f};
        }

    const int lr  = lane >> 3;                 // 0..7 row within an 8-row wave-load
    const int lcs = (((lane & 7) ^ lr) * 8);   // PRE-SWIZZLED global col (bf16 units)

    // one stage = 8 async copies / wave (X:4, Wz:2, Wh:2)
    auto stage = [&](int buf, int k0) {
        short* L = lds + buf * BUFS;
        #pragma unroll
        for (int i = 0; i < 4; ++i) {
            const int r0 = wave * 32 + i * 8;
            async_copy16(Xg + (size_t)(m0 + r0 + lr) * DD + k0 + lcs,
                         &L[r0 * BK]);
        }
        #pragma unroll
        for (int i = 0; i < 2; ++i) {
            const int r0 = wave * 16 + i * 8;
            async_copy16(Wz + (size_t)(n0 + r0 + lr) * DD + k0 + lcs,
                         &L[ZOFF + r0 * BK]);
            async_copy16(Wh + (size_t)(n0 + r0 + lr) * DD + k0 + lcs,
                         &L[HOFF + r0 * BK]);
        }
    };

    // prologue: fill buf0, full drain, barrier
    stage(0, 0);
    asm volatile("s_waitcnt vmcnt(0)" ::: "memory");
    __builtin_amdgcn_s_barrier();
    asm volatile("" ::: "memory");

    const int swz = (col16 & 7) * 8;           // read-side XOR (bf16 units)

    #pragma unroll
    for (int it = 0; it < NIT; ++it) {
        // issue next-tile staging first: HBM latency hides under this tile's MFMAs
        if (it + 1 < NIT) stage((it + 1) & 1, (it + 1) * BK);

        const short* L = lds + (it & 1) * BUFS;
        #pragma unroll
        for (int kk = 0; kk < 2; ++kk) {
            const int ko = (kk * 32 + quad * 8) ^ swz;   // swizzled col offset
            short8 af[4], bzf[2], bhf[2];
            #pragma unroll
            for (int mi = 0; mi < 4; ++mi)
                af[mi] = *(const short8*)&L[(wm*64 + mi*16 + col16) * BK + ko];
            #pragma unroll
            for (int nj = 0; nj < 2; ++nj) {
                bzf[nj] = *(const short8*)&L[ZOFF + (wn*32 + nj*16 + col16) * BK + ko];
                bhf[nj] = *(const short8*)&L[HOFF + (wn*32 + nj*16 + col16) * BK + ko];
            }
            #pragma unroll
            for (int mi = 0; mi < 4; ++mi)
                #pragma unroll
                for (int nj = 0; nj < 2; ++nj) {
                    accz[mi][nj] = __builtin_amdgcn_mfma_f32_16x16x32_bf16(af[mi], bzf[nj], accz[mi][nj], 0, 0, 0);
                    acch[mi][nj] = __builtin_amdgcn_mfma_f32_16x16x32_bf16(af[mi], bhf[nj], acch[mi][nj], 0, 0, 0);
                }
        }
        // drain: next-tile stages landed, this tile's ds_reads retired.
        asm volatile("s_waitcnt vmcnt(0) lgkmcnt(0)" ::: "memory");
        __builtin_amdgcn_s_barrier();
        asm volatile("" ::: "memory");
    }

    // ---- epilogue: gates -> packed bf16, direct TIME-major stores ----
    // C/D layout: col=lane&15 (-> n), row=quad*4+reg (-> m) (m89/m91-verified)
    // m = m0 + wm*64 + mi*16 + quad*4 + reg;  AV addr = m*HH + n.
    {
        const int b  = m0 >> 12;                    // batch
        const int cw = ((m0 & 4095) >> 6) + wm;     // chunk within sequence

        #pragma unroll
        for (int nj = 0; nj < 2; ++nj) {
            const int ln = wn*32 + nj*16 + col16;
            const int n  = n0 + ln;
            const float bzn = bz[n], bhn = bh[n];
            float cA = 1.0f, cV = 0.0f;             // running chunk composite
            #pragma unroll
            for (int mi = 0; mi < 4; ++mi) {
                float sA = 1.0f, sV = 0.0f;         // this thread's 4-t segment
                const size_t mbase = (size_t)(m0 + wm*64 + mi*16 + quad*4) * HH + n;
                #pragma unroll
                for (int reg = 0; reg < 4; ++reg) {
                    const float kz = accz[mi][nj][reg] + bzn;
                    const float kh = acch[mi][nj][reg] + bhn;
                    const float a  = fast_rcp(1.0f + __expf(kz));   // sigmoid(-kz)
                    const float sn = fast_rcp(1.0f + __expf(-kh));  // sigmoid(kh)
                    const float ht = (kh >= 0.0f) ? (kh + 0.5f) : sn;
                    const float v  = (1.0f - a) * ht;               // z * h_tilde
                    const unsigned u = ((unsigned)f2bf(v) << 16) | f2bf(a);
                    AV[mbase + (size_t)reg * HH] = u;
                    const float ar = bf_lo(u), vr = bf_hi(u);       // rounded
                    sV = fmaf(ar, sV, vr);          // t ascending within segment
                    sA *= ar;
                }
                // quad-tree combine (t-order: quad ascending), 16-t composite
                {
                    float oA = __shfl_xor(sA, 16), oV = __shfl_xor(sV, 16);
                    float lA = (quad & 1) ? oA : sA, lV = (quad & 1) ? oV : sV;
                    float rA = (quad & 1) ? sA : oA, rV = (quad & 1) ? sV : oV;
                    sA = lA * rA; sV = fmaf(rA, lV, rV);
                    oA = __shfl_xor(sA, 32); oV = __shfl_xor(sV, 32);
                    lA = (quad & 2) ? oA : sA; lV = (quad & 2) ? oV : sV;
                    rA = (quad & 2) ? sA : oA; rV = (quad & 2) ? sV : oV;
                    sA = lA * rA; sV = fmaf(rA, lV, rV);
                }
                cV = fmaf(sA, cV, sV);              // compose mi segments in order
                cA = cA * sA;
            }
            if (quad == 0)
                cAV[(size_t)cw * BH + b * HH + n] = make_float2(cA, cV);
        }
    }
}

// ---------------------------------------------------------------------------
// Chunk-carry prefix: one thread per channel (b,h). Sequentially composes
// the 64 chunk summaries ONCE, emitting the entering-h for every chunk.
// Grid: 16 blocks x 256 threads = 4096 channels.
// ---------------------------------------------------------------------------
__global__ __launch_bounds__(256)
void chunk_prefix(const float2* __restrict__ cAV, float* __restrict__ H0)
{
    const int ch = blockIdx.x * 256 + threadIdx.x;   // b*HH + h
    float h = 0.5f;                                  // h0 = g(0) = 0.5
    #pragma unroll
    for (int c = 0; c < NC; ++c) {
        H0[(size_t)c * BH + ch] = h;
        const float2 s = cAV[(size_t)c * BH + ch];
        h = fmaf(s.x, h, s.y);
    }
}

// ---------------------------------------------------------------------------
// Scan apply (fp32 out, final layer). 1 channel/thread, TIME-major AV:
// each load is 4B/lane x consecutive h = perfectly coalesced (r7-proven).
// Full unroll (static addresses -> many loads in flight). Carry from H0.
// NT store for `out` (never re-read; keeps L2 for AV).
// ---------------------------------------------------------------------------
__global__ __launch_bounds__(256)
void scan_apply_f32(const unsigned* __restrict__ AV,
                    const float* __restrict__ H0,
                    float* __restrict__ out, float* __restrict__ finals)
{
    const int h = blockIdx.x * 256 + threadIdx.x;
    const int b = blockIdx.y;
    const int c = blockIdx.z;
    const int ch = b * HH + h;
    float hcur = H0[(size_t)c * BH + ch];
    size_t base = ((size_t)(b * SS + c * TCH)) * HH + h;
    #pragma unroll
    for (int tt = 0; tt < TCH; ++tt) {
        const unsigned u = AV[base];
        hcur = fmaf(bf_lo(u), hcur, bf_hi(u));
        __builtin_nontemporal_store(hcur, &out[base]);
        base += HH;
    }
    if (c == NC - 1) finals[ch] = hcur;
}

// ---------------------------------------------------------------------------
// Scan apply (bf16 out): layer-0 hidden seq feeds layer-1's GEMM (Xbf is
// re-read soon -> normal stores). Full unroll as above.
// ---------------------------------------------------------------------------
__global__ __launch_bounds__(256)
void scan_apply_bf16(const unsigned* __restrict__ AV,
                     const float* __restrict__ H0,
                     short* __restrict__ out, float* __restrict__ finals)
{
    const int h = blockIdx.x * 256 + threadIdx.x;
    const int b = blockIdx.y;
    const int c = blockIdx.z;
    const int ch = b * HH + h;
    float hcur = H0[(size_t)c * BH + ch];
    size_t base = ((size_t)(b * SS + c * TCH)) * HH + h;
    #pragma unroll
    for (int tt = 0; tt < TCH; ++tt) {
        const unsigned u = AV[base];
        hcur = fmaf(bf_lo(u), hcur, bf_hi(u));
        out[base] = (short)f2bf(hcur);
        base += HH;
    }
    if (c == NC - 1) finals[ch] = hcur;
}

// ---------------------------------------------------------------------------
// Orchestration.  ws: AV(64MB) Xbf(32MB) Wbf(2MB) cAV(2MB) H0(1MB) ~ 101MB
// ---------------------------------------------------------------------------
extern "C" void kernel_launch(void* const* d_in, const int* in_sizes, int n_in,
                              void* d_out, int out_size, void* d_ws, size_t ws_size,
                              hipStream_t stream)
{
    const float* x   = (const float*)d_in[0];
    const float* wz0 = (const float*)d_in[1];
    const float* bz0 = (const float*)d_in[2];
    const float* wh0 = (const float*)d_in[3];
    const float* bh0 = (const float*)d_in[4];
    const float* wz1 = (const float*)d_in[5];
    const float* bz1 = (const float*)d_in[6];
    const float* wh1 = (const float*)d_in[7];
    const float* bh1 = (const float*)d_in[8];

    float* out    = (float*)d_out;                // (B,S,H) layer-2 hidden seq
    float* finals = out + (size_t)MM * HH;        // (L,B,1,H)

    unsigned* AV  = (unsigned*)d_ws;                      // M*H packed bf16 (v|a), time-major
    short* Xbf    = (short*)(AV + (size_t)MM * HH);       // M*D bf16
    short* Wbf    = Xbf + (size_t)MM * DD;                // 4 * H*D bf16
    float2* cAV   = (float2*)(Wbf + (size_t)4 * HH * DD); // NC*BH float2
    float* H0     = (float*)(cAV + (size_t)NC * BH);      // NC*BH float

    short* Wz0 = Wbf;
    short* Wh0 = Wbf + (size_t)1 * HH * DD;
    short* Wz1 = Wbf + (size_t)2 * HH * DD;
    short* Wh1 = Wbf + (size_t)3 * HH * DD;

    const dim3 gg(MM / BM, HH / BN);       // 256 x 8
    const dim3 gs(HH / 256, BB, NC);       // 2 x 8 x 64 (1 channel/thread)

    // ---- conversions (one launch: X + all 4 weights) ----
    conv_all<<<MM * DD / 8 / 256 + 4 * (HH * DD / 8 / 256), 256, 0, stream>>>(
        x, wz0, wh0, wz1, wh1, Xbf, Wbf);

    // ---- layer 0 ----
    gemm_gate_mfma <<<gg, 256, 0, stream>>>(Xbf, Wz0, bz0, Wh0, bh0, AV, cAV);
    chunk_prefix   <<<BH / 256, 256, 0, stream>>>(cAV, H0);
    scan_apply_bf16<<<gs, 256, 0, stream>>>(AV, H0, Xbf, finals);             // finals[0]

    // ---- layer 1 ----
    gemm_gate_mfma <<<gg, 256, 0, stream>>>(Xbf, Wz1, bz1, Wh1, bh1, AV, cAV);
    chunk_prefix   <<<BH / 256, 256, 0, stream>>>(cAV, H0);
    scan_apply_f32 <<<gs, 256, 0, stream>>>(AV, H0, out, finals + BH);        // finals[1]
}

// Round 10
// 283.268 us; speedup vs baseline: 1.0353x; 1.0151x over previous
//
#include <hip/hip_runtime.h>
#include <math.h>

// Problem constants (from reference)
#define BB 8
#define SS 4096
#define DD 512
#define HH 512
#define MM (BB*SS)          // 32768 rows

// Scan chunking
constexpr int TCH = 64;              // timesteps per chunk
constexpr int NC  = SS / TCH;        // 64 chunks
constexpr int BH  = BB * HH;         // 4096 channels

// MFMA GEMM tiling
constexpr int BM = 128;              // rows per block (= 2 chunks of 64 s)
constexpr int BN = 64;               // cols per block (per weight matrix)
constexpr int BK = 64;               // k per stage

typedef short  short8  __attribute__((ext_vector_type(8)));
typedef float  float4v __attribute__((ext_vector_type(4)));
typedef float  float2v __attribute__((ext_vector_type(2)));

__device__ inline unsigned short f2bf(float f) {
    union { float f; unsigned u; } v; v.f = f;
    unsigned r = v.u + 0x7FFF + ((v.u >> 16) & 1);   // RNE
    return (unsigned short)(r >> 16);
}
__device__ inline float bf_lo(unsigned u) {          // low 16 bits -> float
    union { unsigned u; float f; } x; x.u = u << 16; return x.f;
}
__device__ inline float bf_hi(unsigned u) {          // high 16 bits -> float
    union { unsigned u; float f; } x; x.u = u & 0xffff0000u; return x.f;
}
__device__ inline float fast_rcp(float x) {          // v_rcp_f32, ~1ulp(22b)
    return __builtin_amdgcn_rcpf(x);
}

__device__ inline void async_copy16(const void* g, void* l) {
    __builtin_amdgcn_global_load_lds(
        (const __attribute__((address_space(1))) void*)g,
        (__attribute__((address_space(3))) void*)l, 16, 0, 0);
}

// ---------------------------------------------------------------------------
// fp32 -> bf16 conversion for X (8192 blocks) and the 4 weights (4x128 blocks)
// in a single launch.
// ---------------------------------------------------------------------------
__global__ __launch_bounds__(256)
void conv_all(const float* __restrict__ x,
              const float* __restrict__ w0, const float* __restrict__ w1,
              const float* __restrict__ w2, const float* __restrict__ w3,
              short* __restrict__ Xbf, short* __restrict__ Wbf)
{
    constexpr int XBLK = MM * DD / 8 / 256;   // 8192
    constexpr int WBLK = HH * DD / 8 / 256;   // 128
    const int bid = blockIdx.x;
    const float* src; short* dst; size_t base;
    if (bid < XBLK) {
        src = x; dst = Xbf;
        base = ((size_t)bid * 256 + threadIdx.x) * 8;
    } else {
        const int idx  = bid - XBLK;
        const int wsel = idx / WBLK;
        src = (wsel == 0) ? w0 : (wsel == 1) ? w1 : (wsel == 2) ? w2 : w3;
        dst = Wbf + (size_t)wsel * HH * DD;
        base = ((size_t)(idx % WBLK) * 256 + threadIdx.x) * 8;
    }
    float4 a = *(const float4*)(src + base);
    float4 b = *(const float4*)(src + base + 4);
    short8 r;
    r[0] = f2bf(a.x); r[1] = f2bf(a.y); r[2] = f2bf(a.z); r[3] = f2bf(a.w);
    r[4] = f2bf(b.x); r[5] = f2bf(b.y); r[6] = f2bf(b.z); r[7] = f2bf(b.w);
    *(short8*)(dst + base) = r;
}

// ---------------------------------------------------------------------------
// MFMA gate GEMM + fused chunk-summary scan.  (round-9 proven version,
// byte-identical: 60us, conflicts 0)
//   kz = X[m,:]·Wz[n,:]+bz[n], kh = X[m,:]·Wh[n,:]+bh[n]
//   a = sigmoid(-kz); v = (1-a)*g(kh); AV[m*HH+n] = pack_bf16(v, a)
//
// K-loop: round-4 frozen (T2 XOR-swizzle + 2-phase FULL-DRAIN). CONDEMNED
// (measured): counted-vmcnt (r1,r3 races); in-phase global B loads (r5 FIFO
// serialization); cross-barrier B reg double-buffer (r6 spill); chunk-major
// AV (r8: 4x scan line-transactions).
// Epilogue: direct time-major dword stores (coalesced 64B/quad-row) +
// in-register chunk summary via __shfl_xor quad tree (r8/r9-verified).
// ---------------------------------------------------------------------------
__global__ __launch_bounds__(256)
void gemm_gate_mfma(const short* __restrict__ Xg, const short* __restrict__ Wz,
                    const float* __restrict__ bz, const short* __restrict__ Wh,
                    const float* __restrict__ bh, unsigned* __restrict__ AV,
                    float2* __restrict__ cAV)
{
    __shared__ char smem[65536];               // 2 x 32KB staging
    short* lds = (short*)smem;
    constexpr int BUFS = 16384;                // shorts per buffer (32 KB)
    constexpr int ZOFF = BM * BK;              // 8192  (within buffer)
    constexpr int HOFF = ZOFF + BN * BK;       // 12288 (within buffer)
    constexpr int NIT  = DD / BK;              // 8 K-steps

    const int t    = threadIdx.x;
    const int wave = t >> 6;
    const int lane = t & 63;
    const int col16 = lane & 15;
    const int quad  = lane >> 4;
    const int wm = wave >> 1;          // 0/1: which 64-row half (= chunk)
    const int wn = wave & 1;           // 0/1: which 32-col half
    const int m0 = blockIdx.x * BM;
    const int n0 = blockIdx.y * BN;

    float4v accz[4][2], acch[4][2];
    #pragma unroll
    for (int i = 0; i < 4; ++i)
        #pragma unroll
        for (int j = 0; j < 2; ++j) {
            accz[i][j] = (float4v){0.f, 0.f, 0.f, 0.f};
            acch[i][j] = (float4v){0.f, 0.f, 0.f, 0.f};
        }

    const int lr  = lane >> 3;                 // 0..7 row within an 8-row wave-load
    const int lcs = (((lane & 7) ^ lr) * 8);   // PRE-SWIZZLED global col (bf16 units)

    // one stage = 8 async copies / wave (X:4, Wz:2, Wh:2)
    auto stage = [&](int buf, int k0) {
        short* L = lds + buf * BUFS;
        #pragma unroll
        for (int i = 0; i < 4; ++i) {
            const int r0 = wave * 32 + i * 8;
            async_copy16(Xg + (size_t)(m0 + r0 + lr) * DD + k0 + lcs,
                         &L[r0 * BK]);
        }
        #pragma unroll
        for (int i = 0; i < 2; ++i) {
            const int r0 = wave * 16 + i * 8;
            async_copy16(Wz + (size_t)(n0 + r0 + lr) * DD + k0 + lcs,
                         &L[ZOFF + r0 * BK]);
            async_copy16(Wh + (size_t)(n0 + r0 + lr) * DD + k0 + lcs,
                         &L[HOFF + r0 * BK]);
        }
    };

    // prologue: fill buf0, full drain, barrier
    stage(0, 0);
    asm volatile("s_waitcnt vmcnt(0)" ::: "memory");
    __builtin_amdgcn_s_barrier();
    asm volatile("" ::: "memory");

    const int swz = (col16 & 7) * 8;           // read-side XOR (bf16 units)

    #pragma unroll
    for (int it = 0; it < NIT; ++it) {
        // issue next-tile staging first: HBM latency hides under this tile's MFMAs
        if (it + 1 < NIT) stage((it + 1) & 1, (it + 1) * BK);

        const short* L = lds + (it & 1) * BUFS;
        #pragma unroll
        for (int kk = 0; kk < 2; ++kk) {
            const int ko = (kk * 32 + quad * 8) ^ swz;   // swizzled col offset
            short8 af[4], bzf[2], bhf[2];
            #pragma unroll
            for (int mi = 0; mi < 4; ++mi)
                af[mi] = *(const short8*)&L[(wm*64 + mi*16 + col16) * BK + ko];
            #pragma unroll
            for (int nj = 0; nj < 2; ++nj) {
                bzf[nj] = *(const short8*)&L[ZOFF + (wn*32 + nj*16 + col16) * BK + ko];
                bhf[nj] = *(const short8*)&L[HOFF + (wn*32 + nj*16 + col16) * BK + ko];
            }
            #pragma unroll
            for (int mi = 0; mi < 4; ++mi)
                #pragma unroll
                for (int nj = 0; nj < 2; ++nj) {
                    accz[mi][nj] = __builtin_amdgcn_mfma_f32_16x16x32_bf16(af[mi], bzf[nj], accz[mi][nj], 0, 0, 0);
                    acch[mi][nj] = __builtin_amdgcn_mfma_f32_16x16x32_bf16(af[mi], bhf[nj], acch[mi][nj], 0, 0, 0);
                }
        }
        // drain: next-tile stages landed, this tile's ds_reads retired.
        asm volatile("s_waitcnt vmcnt(0) lgkmcnt(0)" ::: "memory");
        __builtin_amdgcn_s_barrier();
        asm volatile("" ::: "memory");
    }

    // ---- epilogue: gates -> packed bf16, direct TIME-major stores ----
    // C/D layout: col=lane&15 (-> n), row=quad*4+reg (-> m) (m89/m91-verified)
    // m = m0 + wm*64 + mi*16 + quad*4 + reg;  AV addr = m*HH + n.
    {
        const int b  = m0 >> 12;                    // batch
        const int cw = ((m0 & 4095) >> 6) + wm;     // chunk within sequence

        #pragma unroll
        for (int nj = 0; nj < 2; ++nj) {
            const int ln = wn*32 + nj*16 + col16;
            const int n  = n0 + ln;
            const float bzn = bz[n], bhn = bh[n];
            float cA = 1.0f, cV = 0.0f;             // running chunk composite
            #pragma unroll
            for (int mi = 0; mi < 4; ++mi) {
                float sA = 1.0f, sV = 0.0f;         // this thread's 4-t segment
                const size_t mbase = (size_t)(m0 + wm*64 + mi*16 + quad*4) * HH + n;
                #pragma unroll
                for (int reg = 0; reg < 4; ++reg) {
                    const float kz = accz[mi][nj][reg] + bzn;
                    const float kh = acch[mi][nj][reg] + bhn;
                    const float a  = fast_rcp(1.0f + __expf(kz));   // sigmoid(-kz)
                    const float sn = fast_rcp(1.0f + __expf(-kh));  // sigmoid(kh)
                    const float ht = (kh >= 0.0f) ? (kh + 0.5f) : sn;
                    const float v  = (1.0f - a) * ht;               // z * h_tilde
                    const unsigned u = ((unsigned)f2bf(v) << 16) | f2bf(a);
                    AV[mbase + (size_t)reg * HH] = u;
                    const float ar = bf_lo(u), vr = bf_hi(u);       // rounded
                    sV = fmaf(ar, sV, vr);          // t ascending within segment
                    sA *= ar;
                }
                // quad-tree combine (t-order: quad ascending), 16-t composite
                {
                    float oA = __shfl_xor(sA, 16), oV = __shfl_xor(sV, 16);
                    float lA = (quad & 1) ? oA : sA, lV = (quad & 1) ? oV : sV;
                    float rA = (quad & 1) ? sA : oA, rV = (quad & 1) ? sV : oV;
                    sA = lA * rA; sV = fmaf(rA, lV, rV);
                    oA = __shfl_xor(sA, 32); oV = __shfl_xor(sV, 32);
                    lA = (quad & 2) ? oA : sA; lV = (quad & 2) ? oV : sV;
                    rA = (quad & 2) ? sA : oA; rV = (quad & 2) ? sV : oV;
                    sA = lA * rA; sV = fmaf(rA, lV, rV);
                }
                cV = fmaf(sA, cV, sV);              // compose mi segments in order
                cA = cA * sA;
            }
            if (quad == 0)
                cAV[(size_t)cw * BH + b * HH + n] = make_float2(cA, cV);
        }
    }
}

// ---------------------------------------------------------------------------
// Chunk-carry prefix: one thread per channel (b,h). Sequentially composes
// the 64 chunk summaries ONCE, emitting the entering-h for every chunk.
// Grid: 16 blocks x 256 threads = 4096 channels.
// ---------------------------------------------------------------------------
__global__ __launch_bounds__(256)
void chunk_prefix(const float2* __restrict__ cAV, float* __restrict__ H0)
{
    const int ch = blockIdx.x * 256 + threadIdx.x;   // b*HH + h
    float h = 0.5f;                                  // h0 = g(0) = 0.5
    #pragma unroll
    for (int c = 0; c < NC; ++c) {
        H0[(size_t)c * BH + ch] = h;
        const float2 s = cAV[(size_t)c * BH + ch];
        h = fmaf(s.x, h, s.y);
    }
}

// ---------------------------------------------------------------------------
// Scan apply (fp32 out, final layer). 2 channels/thread (G13): uint2 AV
// loads (8B/lane, 512B/wave contiguous), float2 NT stores, float2 H0 load.
// Halves instruction count, doubles ILP on the dependent fma chains.
// Grid (1, B, NC), 512 blocks, 8 waves/CU.
// ---------------------------------------------------------------------------
__global__ __launch_bounds__(256)
void scan_apply_f32(const unsigned* __restrict__ AV,
                    const float* __restrict__ H0,
                    float* __restrict__ out, float* __restrict__ finals)
{
    const int h  = 2 * threadIdx.x;          // channels h, h+1
    const int b  = blockIdx.y;
    const int c  = blockIdx.z;
    const int ch = b * HH + h;
    const float2v h0v = *(const float2v*)&H0[(size_t)c * BH + ch];
    float h0c = h0v[0], h1c = h0v[1];
    size_t base = ((size_t)(b * SS + c * TCH)) * HH + h;
    #pragma unroll
    for (int tt = 0; tt < TCH; ++tt) {
        const uint2 u = *(const uint2*)&AV[base];
        h0c = fmaf(bf_lo(u.x), h0c, bf_hi(u.x));
        h1c = fmaf(bf_lo(u.y), h1c, bf_hi(u.y));
        float2v o; o[0] = h0c; o[1] = h1c;
        __builtin_nontemporal_store(o, (float2v*)&out[base]);
        base += HH;
    }
    if (c == NC - 1) {
        float2v f; f[0] = h0c; f[1] = h1c;
        *(float2v*)&finals[ch] = f;
    }
}

// ---------------------------------------------------------------------------
// Scan apply (bf16 out): layer-0 hidden seq feeds layer-1's GEMM (Xbf is
// re-read soon -> normal stores). 2 channels/thread; packed dword stores.
// ---------------------------------------------------------------------------
__global__ __launch_bounds__(256)
void scan_apply_bf16(const unsigned* __restrict__ AV,
                     const float* __restrict__ H0,
                     short* __restrict__ out, float* __restrict__ finals)
{
    const int h  = 2 * threadIdx.x;
    const int b  = blockIdx.y;
    const int c  = blockIdx.z;
    const int ch = b * HH + h;
    const float2v h0v = *(const float2v*)&H0[(size_t)c * BH + ch];
    float h0c = h0v[0], h1c = h0v[1];
    size_t base = ((size_t)(b * SS + c * TCH)) * HH + h;
    #pragma unroll
    for (int tt = 0; tt < TCH; ++tt) {
        const uint2 u = *(const uint2*)&AV[base];
        h0c = fmaf(bf_lo(u.x), h0c, bf_hi(u.x));
        h1c = fmaf(bf_lo(u.y), h1c, bf_hi(u.y));
        *(unsigned*)&out[base] = (unsigned)f2bf(h0c) | ((unsigned)f2bf(h1c) << 16);
        base += HH;
    }
    if (c == NC - 1) {
        float2v f; f[0] = h0c; f[1] = h1c;
        *(float2v*)&finals[ch] = f;
    }
}

// ---------------------------------------------------------------------------
// Orchestration.  ws: AV(64MB) Xbf(32MB) Wbf(2MB) cAV(2MB) H0(1MB) ~ 101MB
// ---------------------------------------------------------------------------
extern "C" void kernel_launch(void* const* d_in, const int* in_sizes, int n_in,
                              void* d_out, int out_size, void* d_ws, size_t ws_size,
                              hipStream_t stream)
{
    const float* x   = (const float*)d_in[0];
    const float* wz0 = (const float*)d_in[1];
    const float* bz0 = (const float*)d_in[2];
    const float* wh0 = (const float*)d_in[3];
    const float* bh0 = (const float*)d_in[4];
    const float* wz1 = (const float*)d_in[5];
    const float* bz1 = (const float*)d_in[6];
    const float* wh1 = (const float*)d_in[7];
    const float* bh1 = (const float*)d_in[8];

    float* out    = (float*)d_out;                // (B,S,H) layer-2 hidden seq
    float* finals = out + (size_t)MM * HH;        // (L,B,1,H)

    unsigned* AV  = (unsigned*)d_ws;                      // M*H packed bf16 (v|a), time-major
    short* Xbf    = (short*)(AV + (size_t)MM * HH);       // M*D bf16
    short* Wbf    = Xbf + (size_t)MM * DD;                // 4 * H*D bf16
    float2* cAV   = (float2*)(Wbf + (size_t)4 * HH * DD); // NC*BH float2
    float* H0     = (float*)(cAV + (size_t)NC * BH);      // NC*BH float

    short* Wz0 = Wbf;
    short* Wh0 = Wbf + (size_t)1 * HH * DD;
    short* Wz1 = Wbf + (size_t)2 * HH * DD;
    short* Wh1 = Wbf + (size_t)3 * HH * DD;

    const dim3 gg(MM / BM, HH / BN);       // 256 x 8
    const dim3 gs(1, BB, NC);              // 1 x 8 x 64 (2 channels/thread)

    // ---- conversions (one launch: X + all 4 weights) ----
    conv_all<<<MM * DD / 8 / 256 + 4 * (HH * DD / 8 / 256), 256, 0, stream>>>(
        x, wz0, wh0, wz1, wh1, Xbf, Wbf);

    // ---- layer 0 ----
    gemm_gate_mfma <<<gg, 256, 0, stream>>>(Xbf, Wz0, bz0, Wh0, bh0, AV, cAV);
    chunk_prefix   <<<BH / 256, 256, 0, stream>>>(cAV, H0);
    scan_apply_bf16<<<gs, 256, 0, stream>>>(AV, H0, Xbf, finals);             // finals[0]

    // ---- layer 1 ----
    gemm_gate_mfma <<<gg, 256, 0, stream>>>(Xbf, Wz1, bz1, Wh1, bh1, AV, cAV);
    chunk_prefix   <<<BH / 256, 256, 0, stream>>>(cAV, H0);
    scan_apply_f32 <<<gs, 256, 0, stream>>>(AV, H0, out, finals + BH);        // finals[1]
}